// Round 1
// baseline (36.865 us; speedup 1.0000x reference)
//
#include <hip/hip_runtime.h>

// Problem constants (B=4, N=2048 fixed by the reference setup)
#define BB 4
#define NN 2048
#define TM 64              // m-tile per block (staged in LDS)
#define SPLITM (NN / TM)   // 32 m-slices
#define ROWS 2             // n-rows per thread
#define BLK 256            // threads per block
#define RN (ROWS * BLK)    // 512 n-rows per block
#define NGX ((NN / RN) * SPLITM)   // 4 * 32 = 128
#define NBLOCKS (NGX * BB)         // 512
#define INV_TOTAL (1.0f / ((float)BB * (float)NN * (float)NN))

__device__ __forceinline__ void quat_to_R(float qw, float qx, float qy, float qz, float* R) {
    R[0] = 1.f - 2.f * (qy * qy + qz * qz);
    R[1] = 2.f * (qx * qy - qz * qw);
    R[2] = 2.f * (qx * qz + qy * qw);
    R[3] = 2.f * (qx * qy + qz * qw);
    R[4] = 1.f - 2.f * (qx * qx + qz * qz);
    R[5] = 2.f * (qy * qz - qx * qw);
    R[6] = 2.f * (qx * qz - qy * qw);
    R[7] = 2.f * (qy * qz + qx * qw);
    R[8] = 1.f - 2.f * (qx * qx + qy * qy);
}

template <bool ATOMIC>
__global__ __launch_bounds__(BLK) void pair_kernel(
    const float* __restrict__ xyz, const float* __restrict__ scales,
    const float* __restrict__ rot, const float* __restrict__ vel,
    float* __restrict__ partials, float* __restrict__ outp)
{
    __shared__ float smx[TM], smy[TM], smz[TM];
    __shared__ float ssx[TM], ssy[TM], ssz[TM];
    __shared__ float svx[TM], svy[TM], svz[TM];
    __shared__ float sR[9][TM];

    const int tid = threadIdx.x;
    const int b   = blockIdx.y;
    const int nb  = blockIdx.x / SPLITM;   // which 512-row group
    const int ms  = blockIdx.x % SPLITM;   // which 64-m slice
    const int m0  = ms * TM;

    // ---- stage m-tile into LDS (one thread per m) ----
    if (tid < TM) {
        const int m = m0 + tid;
        const size_t b3 = ((size_t)b * NN + m) * 3;
        const size_t b4 = ((size_t)b * NN + m) * 4;
        smx[tid] = xyz[b3 + 0]; smy[tid] = xyz[b3 + 1]; smz[tid] = xyz[b3 + 2];
        ssx[tid] = scales[b3 + 0]; ssy[tid] = scales[b3 + 1]; ssz[tid] = scales[b3 + 2];
        svx[tid] = vel[b3 + 0]; svy[tid] = vel[b3 + 1]; svz[tid] = vel[b3 + 2];
        const float4 q = *reinterpret_cast<const float4*>(rot + b4);
        float R[9];
        quat_to_R(q.x, q.y, q.z, q.w, R);
        #pragma unroll
        for (int k = 0; k < 9; ++k) sR[k][tid] = R[k];
    }

    // ---- per-thread own rows (ROWS of them) ----
    float px[ROWS], py[ROWS], pz[ROWS];
    float sx[ROWS], sy[ROWS], sz[ROWS];
    float vx[ROWS], vy[ROWS], vz[ROWS];
    float Rn[ROWS][9];
    #pragma unroll
    for (int r = 0; r < ROWS; ++r) {
        const int n = nb * RN + r * BLK + tid;
        const size_t b3 = ((size_t)b * NN + n) * 3;
        const size_t b4 = ((size_t)b * NN + n) * 4;
        px[r] = xyz[b3 + 0]; py[r] = xyz[b3 + 1]; pz[r] = xyz[b3 + 2];
        sx[r] = scales[b3 + 0]; sy[r] = scales[b3 + 1]; sz[r] = scales[b3 + 2];
        vx[r] = vel[b3 + 0]; vy[r] = vel[b3 + 1]; vz[r] = vel[b3 + 2];
        const float4 q = *reinterpret_cast<const float4*>(rot + b4);
        quat_to_R(q.x, q.y, q.z, q.w, Rn[r]);
    }

    __syncthreads();

    float acc = 0.f;
    #pragma unroll 4
    for (int j = 0; j < TM; ++j) {
        const float mx = smx[j], my = smy[j], mz = smz[j];
        const float msx = ssx[j], msy = ssy[j], msz = ssz[j];
        const float mvx = svx[j], mvy = svy[j], mvz = svz[j];
        const float Rm0 = sR[0][j], Rm1 = sR[1][j], Rm2 = sR[2][j];
        const float Rm3 = sR[3][j], Rm4 = sR[4][j], Rm5 = sR[5][j];
        const float Rm6 = sR[6][j], Rm7 = sR[7][j], Rm8 = sR[8][j];
        #pragma unroll
        for (int r = 0; r < ROWS; ++r) {
            const float dx = px[r] - mx, dy = py[r] - my, dz = pz[r] - mz;
            const float d2 = fmaf(dx, dx, fmaf(dy, dy, fmaf(dz, dz, 1e-8f)));
            const float rinv = __builtin_amdgcn_rsqf(d2);
            // r_directional(n,m): dir^T * R_n, scaled by s_m (dist factored out via rinv)
            const float a0 = fmaf(dx, Rn[r][0], fmaf(dy, Rn[r][3], dz * Rn[r][6])) * msx;
            const float a1 = fmaf(dx, Rn[r][1], fmaf(dy, Rn[r][4], dz * Rn[r][7])) * msy;
            const float a2 = fmaf(dx, Rn[r][2], fmaf(dy, Rn[r][5], dz * Rn[r][8])) * msz;
            const float qa = __builtin_amdgcn_sqrtf(fmaf(a0, a0, fmaf(a1, a1, a2 * a2)));
            // r_directional(m,n): (-dir)^T * R_m, scaled by s_n (sign irrelevant after square)
            const float b0 = fmaf(dx, Rm0, fmaf(dy, Rm3, dz * Rm6)) * sx[r];
            const float b1 = fmaf(dx, Rm1, fmaf(dy, Rm4, dz * Rm7)) * sy[r];
            const float b2 = fmaf(dx, Rm2, fmaf(dy, Rm5, dz * Rm8)) * sz[r];
            const float qb = __builtin_amdgcn_sqrtf(fmaf(b0, b0, fmaf(b1, b1, b2 * b2)));
            // overlap = relu(r_nm + r_mn - dist) = rinv * relu(qa + qb - d2)
            const float w  = fmaxf(qa + qb - d2, 0.f);
            const float ov = w * rinv;
            const float spec = ov * ov * __builtin_amdgcn_rcpf(fmaf(0.1f, ov, 1.f));
            // v_approach = (v_n - v_m) . diff * rinv
            const float vdot = fmaf(vx[r] - mvx, dx, fmaf(vy[r] - mvy, dy, (vz[r] - mvz) * dz));
            const float ramp = fmaxf(-vdot * rinv, 0.f);
            acc += fmaf(0.1f * ov, ramp, spec);
        }
    }

    // ---- deterministic block reduction ----
    __shared__ float red[BLK];
    red[tid] = acc;
    __syncthreads();
    #pragma unroll
    for (int s = BLK / 2; s > 0; s >>= 1) {
        if (tid < s) red[tid] += red[tid + s];
        __syncthreads();
    }
    if (tid == 0) {
        if (ATOMIC) {
            atomicAdd(outp, red[0] * INV_TOTAL);
        } else {
            partials[blockIdx.y * gridDim.x + blockIdx.x] = red[0];
        }
    }
}

__global__ __launch_bounds__(BLK) void reduce_kernel(const float* __restrict__ partials,
                                                     float* __restrict__ out)
{
    __shared__ float red[BLK];
    const int tid = threadIdx.x;
    float a = 0.f;
    for (int i = tid; i < NBLOCKS; i += BLK) a += partials[i];
    red[tid] = a;
    __syncthreads();
    #pragma unroll
    for (int s = BLK / 2; s > 0; s >>= 1) {
        if (tid < s) red[tid] += red[tid + s];
        __syncthreads();
    }
    if (tid == 0) out[0] = red[0] * INV_TOTAL;
}

extern "C" void kernel_launch(void* const* d_in, const int* in_sizes, int n_in,
                              void* d_out, int out_size, void* d_ws, size_t ws_size,
                              hipStream_t stream)
{
    const float* xyz    = (const float*)d_in[0];
    const float* scales = (const float*)d_in[1];
    const float* rot    = (const float*)d_in[2];
    const float* vel    = (const float*)d_in[3];
    float* out = (float*)d_out;

    dim3 grid(NGX, BB);
    if (ws_size >= NBLOCKS * sizeof(float)) {
        float* partials = (float*)d_ws;
        pair_kernel<false><<<grid, BLK, 0, stream>>>(xyz, scales, rot, vel, partials, out);
        reduce_kernel<<<1, BLK, 0, stream>>>(partials, out);
    } else {
        // Fallback: atomic accumulation (out zeroed first; capture-safe memset)
        hipMemsetAsync(d_out, 0, sizeof(float), stream);
        pair_kernel<true><<<grid, BLK, 0, stream>>>(xyz, scales, rot, vel, nullptr, out);
    }
}